// Round 1
// baseline (5174.589 us; speedup 1.0000x reference)
//
#include <hip/hip_runtime.h>
#include <math.h>

// GlimpseDecoder: B=512, N=T=200, D=128, H=8, dk=16
// Strategy: decode loop is independent per batch element -> 1 block per b,
// whole 200-step loop inside one kernel, no grid sync needed.

#define Bsz 512
#define Nn  200
#define Dd  128
#define Hh  8
#define DKk 16
#define TANH_CLIP 10.0f
#define NEG_INF  -1e9f

// ---------------- Kernel A: proj = emb @ W_node -> gk, gv, lk ----------------
// grid = B*N/32 blocks, 384 threads. Each block: 32 rows x 384 cols.
__global__ __launch_bounds__(384) void proj_kernel(
    const float* __restrict__ emb, const float* __restrict__ Wn,
    float* __restrict__ gk, float* __restrict__ gv, float* __restrict__ lk)
{
    __shared__ float e[32][Dd];
    const int rowBase = blockIdx.x * 32;
    const int tid = threadIdx.x;
    for (int i = tid; i < 32 * Dd; i += 384)
        e[i >> 7][i & 127] = emb[(size_t)rowBase * Dd + i];
    __syncthreads();

    float acc[32];
#pragma unroll
    for (int r = 0; r < 32; ++r) acc[r] = 0.f;

    for (int k = 0; k < Dd; ++k) {
        float w = Wn[k * 384 + tid];   // column tid of W_node, coalesced, L2-hot
#pragma unroll
        for (int r = 0; r < 32; ++r) acc[r] = fmaf(e[r][k], w, acc[r]);
    }

    float* outArr = (tid < 128) ? gk : (tid < 256) ? gv : lk;
    const int jj = tid & 127;
#pragma unroll
    for (int r = 0; r < 32; ++r)
        outArr[(size_t)(rowBase + r) * Dd + jj] = acc[r];
}

// ---------------- Kernel B: full greedy decode, 1 block per batch elem -------
__global__ __launch_bounds__(256) void decode_kernel(
    const float* __restrict__ emb,
    const float* __restrict__ Wf,   // W_fixed [D][D]
    const float* __restrict__ Ws,   // W_step  [D][D]
    const float* __restrict__ gk, const float* __restrict__ gv,
    const float* __restrict__ lk,
    float* __restrict__ out_logp,   // [B][T][N]
    float* __restrict__ out_pi)     // [B][T] (as float)
{
    const int b   = blockIdx.x;
    const int tid = threadIdx.x;
    const int wv  = tid >> 6;
    const int lane = tid & 63;

    __shared__ __align__(16) float ctx[Dd];
    __shared__ __align__(16) float fixedc[Dd];
    __shared__ __align__(16) float q[Dd];
    __shared__ __align__(16) float glim[Dd];
    __shared__ float sm[Hh][Nn];        // compat -> normalized attn
    __shared__ float logits_s[Nn];
    __shared__ unsigned char visited[Nn];
    __shared__ float red_v[4];
    __shared__ int   red_i[4];
    __shared__ float red_s[4];
    __shared__ float m_sh, lse_sh;
    __shared__ int   sel_sh;

    const float inv_sqrt_dk = 0.25f;                 // 1/sqrt(16)
    const float inv_sqrt_d  = 0.08838834764831845f;  // 1/sqrt(128)

    const float* embB = emb + (size_t)b * Nn * Dd;
    const float* gkB  = gk  + (size_t)b * Nn * Dd;
    const float* gvB  = gv  + (size_t)b * Nn * Dd;
    const float* lkB  = lk  + (size_t)b * Nn * Dd;

    // ---- prologue: graph_emb (mean) -> ctx ; fixed_ctx = graph_emb @ W_fixed
    for (int i = tid; i < Nn; i += 256) visited[i] = 0;
    if (tid < Dd) {
        float s = 0.f;
        for (int n = 0; n < Nn; ++n) s += embB[n * Dd + tid];
        ctx[tid] = s * (1.0f / (float)Nn);
    }
    __syncthreads();
    if (tid < Dd) {
        float s = 0.f;
#pragma unroll 8
        for (int k = 0; k < Dd; ++k) s = fmaf(ctx[k], Wf[k * Dd + tid], s);
        fixedc[tid] = s;
    }
    __syncthreads();

    // ---- decode loop ----
    for (int t = 0; t < Nn; ++t) {
        // 1) q = fixed_ctx + ctx @ W_step
        if (tid < Dd) {
            float s = 0.f;
#pragma unroll 8
            for (int k = 0; k < Dd; ++k) s = fmaf(ctx[k], Ws[k * Dd + tid], s);
            q[tid] = fixedc[tid] + s;
        }
        __syncthreads();

        // 2) compat[h][n] = (q_h . gK_{n,h}) * inv_sqrt_dk, masked
        for (int item = tid; item < Nn * Hh; item += 256) {
            const int n = item >> 3, h = item & 7;
            const float4* g4 = (const float4*)(gkB + (size_t)n * Dd + h * DKk);
            const float4* q4 = (const float4*)(q + h * DKk);
            float s = 0.f;
#pragma unroll
            for (int i = 0; i < 4; ++i) {
                float4 a = g4[i]; float4 c = q4[i];
                s += a.x * c.x + a.y * c.y + a.z * c.z + a.w * c.w;
            }
            s *= inv_sqrt_dk;
            sm[h][n] = visited[n] ? NEG_INF : s;
        }
        __syncthreads();

        // 3) per-head softmax (wave wv handles heads 2wv, 2wv+1), normalize in LDS
        for (int h = 2 * wv; h < 2 * wv + 2; ++h) {
            float m = -INFINITY;
            for (int n = lane; n < Nn; n += 64) m = fmaxf(m, sm[h][n]);
#pragma unroll
            for (int off = 32; off > 0; off >>= 1) m = fmaxf(m, __shfl_xor(m, off));
            float s = 0.f;
            for (int n = lane; n < Nn; n += 64) {
                float p = expf(sm[h][n] - m);
                sm[h][n] = p;
                s += p;
            }
#pragma unroll
            for (int off = 32; off > 0; off >>= 1) s += __shfl_xor(s, off);
            const float inv = 1.0f / s;
            for (int n = lane; n < Nn; n += 64) sm[h][n] *= inv;
        }
        __syncthreads();

        // 4) glimpse[d] = sum_n attn[h(d)][n] * gV[n][d]
        if (tid < Dd) {
            const int h = tid >> 4;
            float s = 0.f;
            for (int n = 0; n < Nn; ++n) s = fmaf(sm[h][n], gvB[(size_t)n * Dd + tid], s);
            glim[tid] = s;
        }
        __syncthreads();

        // 5) logits[n] = clip*tanh((glimpse . lK_n) * inv_sqrt_d), masked
        for (int item = tid; item < Nn * 8; item += 256) {
            const int n = item >> 3, p = item & 7;
            const float4* l4 = (const float4*)(lkB + (size_t)n * Dd + p * 16);
            const float4* g4 = (const float4*)(glim + p * 16);
            float s = 0.f;
#pragma unroll
            for (int i = 0; i < 4; ++i) {
                float4 a = l4[i]; float4 c = g4[i];
                s += a.x * c.x + a.y * c.y + a.z * c.z + a.w * c.w;
            }
            s += __shfl_xor(s, 1);
            s += __shfl_xor(s, 2);
            s += __shfl_xor(s, 4);
            if (p == 0) {
                float v = TANH_CLIP * tanhf(s * inv_sqrt_d);
                logits_s[n] = visited[n] ? NEG_INF : v;
            }
        }
        __syncthreads();

        // 6) block max + argmax (first index on ties)
        float v = (tid < Nn) ? logits_s[tid] : -INFINITY;
        int   idx = tid;
#pragma unroll
        for (int off = 32; off > 0; off >>= 1) {
            float ov = __shfl_xor(v, off);
            int   oi = __shfl_xor(idx, off);
            if (ov > v || (ov == v && oi < idx)) { v = ov; idx = oi; }
        }
        if (lane == 0) { red_v[wv] = v; red_i[wv] = idx; }
        __syncthreads();
        if (tid == 0) {
            float bm = red_v[0]; int bi = red_i[0];
#pragma unroll
            for (int i = 1; i < 4; ++i)
                if (red_v[i] > bm || (red_v[i] == bm && red_i[i] < bi)) { bm = red_v[i]; bi = red_i[i]; }
            m_sh = bm; sel_sh = bi;
        }
        __syncthreads();
        const float m = m_sh;
        const int sel = sel_sh;

        // 7) logsumexp
        float e = (tid < Nn) ? expf(logits_s[tid] - m) : 0.f;
#pragma unroll
        for (int off = 32; off > 0; off >>= 1) e += __shfl_xor(e, off);
        if (lane == 0) red_s[wv] = e;
        __syncthreads();
        if (tid == 0) lse_sh = logf(red_s[0] + red_s[1] + red_s[2] + red_s[3]) + m;
        __syncthreads();
        const float lse = lse_sh;

        // 8) write outputs
        if (tid < Nn)
            out_logp[((size_t)b * Nn + t) * Nn + tid] = logits_s[tid] - lse;
        if (tid == 0)
            out_pi[(size_t)b * Nn + t] = (float)sel;

        // 9) update state
        if (tid == 0) visited[sel] = 1;
        if (tid < Dd) ctx[tid] = embB[(size_t)sel * Dd + tid];
        __syncthreads();
    }
}

// ----------------------------------------------------------------------------
extern "C" void kernel_launch(void* const* d_in, const int* in_sizes, int n_in,
                              void* d_out, int out_size, void* d_ws, size_t ws_size,
                              hipStream_t stream) {
    const float* emb = (const float*)d_in[0];   // [B,N,D]
    const float* Wn  = (const float*)d_in[1];   // [D,3D]
    const float* Wf  = (const float*)d_in[2];   // [D,D]
    const float* Wsp = (const float*)d_in[3];   // [D,D]

    const size_t BND = (size_t)Bsz * Nn * Dd;   // 13,107,200 floats
    float* gk = (float*)d_ws;                   // needs 3*BND*4 = 157 MB of ws
    float* gv = gk + BND;
    float* lk = gv + BND;

    float* out_logp = (float*)d_out;                       // [B,T,N]
    float* out_pi   = out_logp + (size_t)Bsz * Nn * Nn;    // [B,T] as float

    proj_kernel<<<(Bsz * Nn) / 32, 384, 0, stream>>>(emb, Wn, gk, gv, lk);
    decode_kernel<<<Bsz, 256, 0, stream>>>(emb, Wf, Wsp, gk, gv, lk,
                                           out_logp, out_pi);
}

// Round 2
// 1828.436 us; speedup vs baseline: 2.8301x; 2.8301x over previous
//
#include <hip/hip_runtime.h>
#include <math.h>

// GlimpseDecoder: B=512, N=T=200, D=128, H=8, dk=16
// R2: decode keeps the entire per-b working set on-chip:
//   emb_b -> LDS (102KB), gk/gv/lk/W_step -> registers (~210 VGPR).
// Per-step global traffic ~= output writes only.

#define Bsz 512
#define Nn  200
#define Dd  128
#define TANH_CLIP 10.0f
#define NEG_INF  -1e9f

__device__ __forceinline__ float dot4(float4 a, float4 b) {
    return a.x*b.x + a.y*b.y + a.z*b.z + a.w*b.w;
}

// ---------------- Kernel A: proj = emb @ W_node -> gk, gv, lk ----------------
__global__ __launch_bounds__(384) void proj_kernel(
    const float* __restrict__ emb, const float* __restrict__ Wn,
    float* __restrict__ gk, float* __restrict__ gv, float* __restrict__ lk)
{
    __shared__ float e[32][Dd];
    const int rowBase = blockIdx.x * 32;
    const int tid = threadIdx.x;
    for (int i = tid; i < 32 * Dd; i += 384)
        e[i >> 7][i & 127] = emb[(size_t)rowBase * Dd + i];
    __syncthreads();

    float acc[32];
#pragma unroll
    for (int r = 0; r < 32; ++r) acc[r] = 0.f;

    for (int k = 0; k < Dd; ++k) {
        float w = Wn[k * 384 + tid];
#pragma unroll
        for (int r = 0; r < 32; ++r) acc[r] = fmaf(e[r][k], w, acc[r]);
    }

    float* outArr = (tid < 128) ? gk : (tid < 256) ? gv : lk;
    const int jj = tid & 127;
#pragma unroll
    for (int r = 0; r < 32; ++r)
        outArr[(size_t)(rowBase + r) * Dd + jj] = acc[r];
}

// ---------------- Kernel B: full greedy decode, on-chip working set ----------
__global__ __launch_bounds__(512) void decode_kernel(
    const float* __restrict__ emb,
    const float* __restrict__ Wf,   // W_fixed [D][D]
    const float* __restrict__ Wsp,  // W_step  [D][D]
    const float* __restrict__ gk, const float* __restrict__ gv,
    const float* __restrict__ lk,
    float* __restrict__ out_logp,   // [B][T][N]
    float* __restrict__ out_pi)     // [B][T] (as float)
{
    const int b    = blockIdx.x;
    const int t    = threadIdx.x;
    const int g    = t >> 7;      // 0..3
    const int d    = t & 127;     // 0..127
    const int lane = t & 63;
    const int w    = t >> 6;      // wave 0..7 == head for softmax
    const int h_c  = t & 7;       // compat head owned by this thread
    const int n_c  = t >> 3;      // compat base n (0..63)

    __shared__ __align__(16) float emb_s[Nn * Dd];     // 102400 B
    __shared__ __align__(16) float sm_raw[8][200];     // 6400
    __shared__ __align__(16) float sm2[8][4][52];      // 6656 (aligned 52-pad)
    __shared__ __align__(16) float red[4][128];        // 2048
    __shared__ __align__(16) float q_s[128];
    __shared__ __align__(16) float fixedc_s[128];
    __shared__ __align__(16) float glim_s[128];
    __shared__ __align__(16) float ctx0_s[128];
    __shared__ float logits_s[200];
    __shared__ unsigned char visited[200];

    const float inv_sqrt_d = 0.08838834764831845f;  // 1/sqrt(128)

    const float* embB = emb + (size_t)b * Nn * Dd;
    const float* gkB  = gk  + (size_t)b * Nn * Dd;
    const float* gvB  = gv  + (size_t)b * Nn * Dd;
    const float* lkB  = lk  + (size_t)b * Nn * Dd;

    // ---------------- persistent register storage ----------------
    float4 gk0[4], gk1[4], gk2[4];
    float4 gk3[4] = {};          // only threads t<64 use this
    float  gv_r[50];
    float4 lk_r[16] = {};        // only threads t<400 use this
    float  ws_r[32];

    // ---------------- load phase ----------------
    {   // emb -> LDS (float4 coalesced)
        const float4* e4  = (const float4*)embB;
        float4*       es4 = (float4*)emb_s;
#pragma unroll
        for (int it = 0; it < 12; ++it) es4[t + 512 * it] = e4[t + 512 * it];
        if (t < 256) es4[t + 6144] = e4[t + 6144];
    }
    {   // gk pairs: pair p -> n=p>>3, h=p&7 (h == h_c for all pairs)
        const float4* s0 = (const float4*)(gkB + (size_t)(n_c      ) * Dd + h_c * 16);
        const float4* s1 = (const float4*)(gkB + (size_t)(n_c +  64) * Dd + h_c * 16);
        const float4* s2 = (const float4*)(gkB + (size_t)(n_c + 128) * Dd + h_c * 16);
        gk0[0]=s0[0]; gk0[1]=s0[1]; gk0[2]=s0[2]; gk0[3]=s0[3];
        gk1[0]=s1[0]; gk1[1]=s1[1]; gk1[2]=s1[2]; gk1[3]=s1[3];
        gk2[0]=s2[0]; gk2[1]=s2[1]; gk2[2]=s2[2]; gk2[3]=s2[3];
        if (t < 64) {
            const float4* s3 = (const float4*)(gkB + (size_t)(n_c + 192) * Dd + h_c * 16);
            gk3[0]=s3[0]; gk3[1]=s3[1]; gk3[2]=s3[2]; gk3[3]=s3[3];
        }
    }
#pragma unroll
    for (int k = 0; k < 50; ++k) gv_r[k] = gvB[(size_t)(50 * g + k) * Dd + d];
    if (t < 400) {
        const float4* src = (const float4*)(lkB + (size_t)(t >> 1) * Dd + (t & 1) * 64);
#pragma unroll
        for (int i = 0; i < 16; ++i) lk_r[i] = src[i];
    }
#pragma unroll
    for (int j = 0; j < 32; ++j) ws_r[j] = Wsp[(32 * g + j) * Dd + d];
    if (t < 200) visited[t] = 0;
    __syncthreads();

    // ---------------- prologue: ctx0 = mean(emb), fixedc = ctx0 @ W_fixed ----
    {
        float s = 0.f;
#pragma unroll
        for (int k = 0; k < 50; ++k) s += emb_s[(50 * g + k) * Dd + d];
        red[g][d] = s;
    }
    __syncthreads();
    if (t < 128) ctx0_s[t] = (red[0][t] + red[1][t] + red[2][t] + red[3][t]) * (1.0f / 200.0f);
    __syncthreads();
    {
        float s = 0.f;
#pragma unroll
        for (int j = 0; j < 32; ++j)
            s = fmaf(ctx0_s[32 * g + j], Wf[(32 * g + j) * Dd + d], s);
        red[g][d] = s;
    }
    __syncthreads();
    if (t < 128) fixedc_s[t] = red[0][t] + red[1][t] + red[2][t] + red[3][t];
    __syncthreads();

    // ---------------- decode loop ----------------
    int sel_prev = 0;
    for (int step = 0; step < Nn; ++step) {
        // A) q partial: q = fixedc + ctx @ W_step ; ctx is ctx0 (step 0) or emb row
        {
            const float* ctxp = (step == 0) ? ctx0_s : (emb_s + sel_prev * Dd);
            const float4* c4 = (const float4*)(ctxp + 32 * g);
            float s = 0.f;
#pragma unroll
            for (int j4 = 0; j4 < 8; ++j4) {
                float4 c = c4[j4];
                s = fmaf(c.x, ws_r[4 * j4 + 0], s);
                s = fmaf(c.y, ws_r[4 * j4 + 1], s);
                s = fmaf(c.z, ws_r[4 * j4 + 2], s);
                s = fmaf(c.w, ws_r[4 * j4 + 3], s);
            }
            red[g][d] = s;
        }
        __syncthreads();                                   // B1
        if (t < 128) q_s[t] = fixedc_s[t] + red[0][t] + red[1][t] + red[2][t] + red[3][t];
        __syncthreads();                                   // B2

        // C) compat: in-register dot16 per (n,h) pair
        {
            const float4* qq = (const float4*)(q_s + 16 * h_c);
            float4 qa0 = qq[0], qa1 = qq[1], qa2 = qq[2], qa3 = qq[3];
#define DOPAIR(GK, NN) do { \
            float s_ = dot4(GK[0], qa0) + dot4(GK[1], qa1) + dot4(GK[2], qa2) + dot4(GK[3], qa3); \
            s_ *= 0.25f; \
            sm_raw[h_c][NN] = visited[NN] ? NEG_INF : s_; } while (0)
            DOPAIR(gk0, n_c);
            DOPAIR(gk1, n_c + 64);
            DOPAIR(gk2, n_c + 128);
            if (t < 64) DOPAIR(gk3, n_c + 192);
#undef DOPAIR
        }
        __syncthreads();                                   // B3

        // D) per-head softmax (wave w == head w), write normalized attn to sm2
        {
            const float* row = sm_raw[w];
            float x0 = row[lane], x1 = row[lane + 64], x2 = row[lane + 128];
            float x3 = (lane < 8) ? row[lane + 192] : -INFINITY;
            float m = fmaxf(fmaxf(x0, x1), fmaxf(x2, x3));
#pragma unroll
            for (int off = 1; off < 64; off <<= 1) m = fmaxf(m, __shfl_xor(m, off));
            float p0 = expf(x0 - m), p1 = expf(x1 - m), p2 = expf(x2 - m);
            float p3 = (lane < 8) ? expf(x3 - m) : 0.f;
            float ssum = p0 + p1 + p2 + p3;
#pragma unroll
            for (int off = 1; off < 64; off <<= 1) ssum += __shfl_xor(ssum, off);
            float inv = 1.0f / ssum;
            p0 *= inv; p1 *= inv; p2 *= inv; p3 *= inv;
            int n0 = lane, n1 = lane + 64, n2 = lane + 128;
            sm2[w][n0 / 50][n0 % 50] = p0;
            sm2[w][n1 / 50][n1 % 50] = p1;
            sm2[w][n2 / 50][n2 % 50] = p2;
            if (lane < 8) sm2[w][3][42 + lane] = p3;
        }
        __syncthreads();                                   // B4

        // E) glimpse partial: glim[d] += attn[h(d)][n] * gv[n][d] over owned n
        {
            const int hd = d >> 4;
            const float* a = &sm2[hd][g][0];
            float s = 0.f;
#pragma unroll
            for (int k4 = 0; k4 < 12; ++k4) {
                float4 av = ((const float4*)a)[k4];
                s = fmaf(av.x, gv_r[4 * k4 + 0], s);
                s = fmaf(av.y, gv_r[4 * k4 + 1], s);
                s = fmaf(av.z, gv_r[4 * k4 + 2], s);
                s = fmaf(av.w, gv_r[4 * k4 + 3], s);
            }
            s = fmaf(a[48], gv_r[48], s);
            s = fmaf(a[49], gv_r[49], s);
            red[g][d] = s;
        }
        __syncthreads();                                   // B5
        if (t < 128) glim_s[t] = red[0][t] + red[1][t] + red[2][t] + red[3][t];
        __syncthreads();                                   // B6

        // G) logits: t<400, (n = t>>1, half j = t&1), dot64 + 1 shuffle
        if (t < 400) {
            const int n = t >> 1, j = t & 1;
            const float4* gl = ((const float4*)glim_s) + 16 * j;
            float s = 0.f;
#pragma unroll
            for (int i = 0; i < 16; ++i) s += dot4(lk_r[i], gl[i]);
            s += __shfl_xor(s, 1);
            if (j == 0) {
                float v = TANH_CLIP * tanhf(s * inv_sqrt_d);
                logits_s[n] = visited[n] ? NEG_INF : v;
            }
        }
        __syncthreads();                                   // B7

        // H) redundant per-wave argmax + logsumexp (no barriers needed)
        float v0 = logits_s[lane], v1 = logits_s[lane + 64], v2 = logits_s[lane + 128];
        float v3 = (lane < 8) ? logits_s[lane + 192] : -INFINITY;
        float bv = v0; int bi = lane;
        if (v1 > bv) { bv = v1; bi = lane + 64; }
        if (v2 > bv) { bv = v2; bi = lane + 128; }
        if (v3 > bv) { bv = v3; bi = lane + 192; }
#pragma unroll
        for (int off = 1; off < 64; off <<= 1) {
            float ov = __shfl_xor(bv, off);
            int   oi = __shfl_xor(bi, off);
            if (ov > bv || (ov == bv && oi < bi)) { bv = ov; bi = oi; }
        }
        const float m   = bv;
        const int   sel = bi;
        float e = expf(v0 - m) + expf(v1 - m) + expf(v2 - m)
                + ((lane < 8) ? expf(v3 - m) : 0.f);
#pragma unroll
        for (int off = 1; off < 64; off <<= 1) e += __shfl_xor(e, off);
        const float lse = logf(e) + m;

        // I) outputs + state update (next barrier is B1 of next step)
        if (t < 200) out_logp[((size_t)b * Nn + step) * Nn + t] = logits_s[t] - lse;
        if (t == 0) {
            out_pi[(size_t)b * Nn + step] = (float)sel;
            visited[sel] = 1;
        }
        sel_prev = sel;
    }
}

// ----------------------------------------------------------------------------
extern "C" void kernel_launch(void* const* d_in, const int* in_sizes, int n_in,
                              void* d_out, int out_size, void* d_ws, size_t ws_size,
                              hipStream_t stream) {
    (void)in_sizes; (void)n_in; (void)out_size; (void)ws_size;
    const float* emb = (const float*)d_in[0];   // [B,N,D]
    const float* Wn  = (const float*)d_in[1];   // [D,3D]
    const float* Wf  = (const float*)d_in[2];   // [D,D]
    const float* Wsp = (const float*)d_in[3];   // [D,D]

    const size_t BND = (size_t)Bsz * Nn * Dd;
    float* gk = (float*)d_ws;
    float* gv = gk + BND;
    float* lk = gv + BND;

    float* out_logp = (float*)d_out;                       // [B,T,N]
    float* out_pi   = out_logp + (size_t)Bsz * Nn * Nn;    // [B,T] as float

    proj_kernel<<<(Bsz * Nn) / 32, 384, 0, stream>>>(emb, Wn, gk, gv, lk);
    decode_kernel<<<Bsz, 512, 0, stream>>>(emb, Wf, Wsp, gk, gv, lk,
                                           out_logp, out_pi);
}

// Round 3
// 1806.176 us; speedup vs baseline: 2.8649x; 1.0123x over previous
//
#include <hip/hip_runtime.h>
#include <math.h>

// GlimpseDecoder: B=512, N=T=200, D=128, H=8, dk=16
// R3: critical-path decode. 4 barriers/step, per-wave fused compat+softmax,
// register visited-masks, ballot argmax, readlane q broadcast.

#define Bsz 512
#define Nn  200
#define Dd  128
#define TANH_CLIP 10.0f
#define NEG_INF  -1e9f
#define LOG2E 1.4426950408889634f
#define LN2   0.6931471805599453f

__device__ __forceinline__ float dot4(float4 a, float4 b) {
    return a.x*b.x + a.y*b.y + a.z*b.z + a.w*b.w;
}
__device__ __forceinline__ float rdlane(float v, int l) {
    union { float f; int i; } u; u.f = v;
    u.i = __builtin_amdgcn_readlane(u.i, l);
    return u.f;
}

// ---------------- Kernel A: proj = emb @ W_node -> gk, gv, lk ----------------
// 64 rows/block to halve W_node re-fetch vs R2.
__global__ __launch_bounds__(384) void proj_kernel(
    const float* __restrict__ emb, const float* __restrict__ Wn,
    float* __restrict__ gk, float* __restrict__ gv, float* __restrict__ lk)
{
    __shared__ float e[64][Dd];          // 32 KB
    const int rowBase = blockIdx.x * 64;
    const int tid = threadIdx.x;
    const float4* e4  = (const float4*)(emb + (size_t)rowBase * Dd);
    float4*       es4 = (float4*)&e[0][0];
    for (int i = tid; i < 64 * Dd / 4; i += 384) es4[i] = e4[i];
    __syncthreads();

    float acc[64];
#pragma unroll
    for (int r = 0; r < 64; ++r) acc[r] = 0.f;

    for (int k = 0; k < Dd; ++k) {
        float wv = Wn[k * 384 + tid];    // coalesced, L2-hot
#pragma unroll
        for (int r = 0; r < 64; ++r) acc[r] = fmaf(e[r][k], wv, acc[r]);  // broadcast LDS
    }

    float* outArr = (tid < 128) ? gk : (tid < 256) ? gv : lk;
    const int jj = tid & 127;
#pragma unroll
    for (int r = 0; r < 64; ++r)
        outArr[(size_t)(rowBase + r) * Dd + jj] = acc[r];
}

// ---------------- Kernel B: full greedy decode ----------
__global__ __launch_bounds__(512, 2) void decode_kernel(
    const float* __restrict__ emb,
    const float* __restrict__ Wf,   // W_fixed [D][D]
    const float* __restrict__ Wsp,  // W_step  [D][D]
    const float* __restrict__ gk, const float* __restrict__ gv,
    const float* __restrict__ lk,
    float* __restrict__ out_logp,   // [B][T][N]
    float* __restrict__ out_pi)     // [B][T] (as float)
{
    const int b    = blockIdx.x;
    const int t    = threadIdx.x;
    const int lane = t & 63;
    const int w    = t >> 6;      // wave id == attention head
    const int g    = t >> 7;      // 0..3 reduction group
    const int d    = t & 127;     // 0..127 output column
    const int jq   = lane >> 2;   // q column within head (0..15)
    const int kk   = lane & 3;    // k-chunk (0..3)

    __shared__ __align__(16) float emb_s[Nn * Dd];   // 100 KB
    __shared__ __align__(16) float sm2[8][264];      // unnormalized attn p, idx n=lane+64k
    __shared__ __align__(16) float red[4][128];
    __shared__ __align__(16) float fixedc_s[128];
    __shared__ __align__(16) float ctx0_s[128];
    __shared__ __align__(16) float glim_s[128];
    __shared__ float logits_s[200];
    __shared__ float sums[8];

    const float inv_sqrt_d = 0.08838834764831845f;  // 1/sqrt(128)
    const float QSCALE = 0.25f * LOG2E;             // fold 1/sqrt(dk) and log2(e)

    const float* embB = emb + (size_t)b * Nn * Dd;
    const float* gkB  = gk  + (size_t)b * Nn * Dd;
    const float* gvB  = gv  + (size_t)b * Nn * Dd;
    const float* lkB  = lk  + (size_t)b * Nn * Dd;

    // ---------------- persistent registers ----------------
    float4 gk0[4], gk1[4], gk2[4], gk3[4];  // K frags: head w, n = lane+64k
    float  gv_r[52];                        // V rows 52g..52g+51 (clamped), col d
    float4 lk_r[16];                        // logit-K: t<400: n=t>>1, half t&1
    float  ws_r[32];                        // W_step[32kk + rot][16w+jq]

    // ---------------- load phase ----------------
    {
        const float4* e4  = (const float4*)embB;
        float4*       es4 = (float4*)emb_s;
#pragma unroll
        for (int it = 0; it < 12; ++it) es4[t + 512 * it] = e4[t + 512 * it];
        if (t < 256) es4[t + 6144] = e4[t + 6144];
    }
    {
        const float4* s0 = (const float4*)(gkB + (size_t)(lane      ) * Dd + 16 * w);
        const float4* s1 = (const float4*)(gkB + (size_t)(lane +  64) * Dd + 16 * w);
        const float4* s2 = (const float4*)(gkB + (size_t)(lane + 128) * Dd + 16 * w);
        const int n3 = (lane < 8) ? lane + 192 : 199;
        const float4* s3 = (const float4*)(gkB + (size_t)n3 * Dd + 16 * w);
#pragma unroll
        for (int i = 0; i < 4; ++i) { gk0[i]=s0[i]; gk1[i]=s1[i]; gk2[i]=s2[i]; gk3[i]=s3[i]; }
    }
#pragma unroll
    for (int k = 0; k < 52; ++k) {
        int r = 52 * g + k; r = r < 200 ? r : 199;
        gv_r[k] = gvB[(size_t)r * Dd + d];
    }
    if (t < 400) {
        const float4* src = (const float4*)(lkB + (size_t)(t >> 1) * Dd + (t & 1) * 64);
#pragma unroll
        for (int i = 0; i < 16; ++i) lk_r[i] = src[i];
    } else {
#pragma unroll
        for (int i = 0; i < 16; ++i) lk_r[i] = float4{0,0,0,0};
    }
#pragma unroll
    for (int i4 = 0; i4 < 8; ++i4) {
        const int kbase = 32 * kk + 4 * ((i4 + 2 * kk) & 7);   // rotated for bank-free ctx reads
#pragma unroll
        for (int m = 0; m < 4; ++m)
            ws_r[4 * i4 + m] = Wsp[(size_t)(kbase + m) * Dd + 16 * w + jq];
    }
    __syncthreads();

    // ---------------- prologue: ctx0 = mean(emb); fixedc = ctx0 @ W_fixed ----
    {
        float s = 0.f;
#pragma unroll
        for (int k = 0; k < 52; ++k) {
            int r = 52 * g + k;
            if (r < 200) s += emb_s[r * Dd + d];
        }
        red[g][d] = s;
    }
    __syncthreads();
    if (t < 128) ctx0_s[t] = (red[0][t] + red[1][t] + red[2][t] + red[3][t]) * (1.0f / 200.0f);
    __syncthreads();
    {
        float s = 0.f;
#pragma unroll
        for (int j = 0; j < 32; ++j)
            s = fmaf(ctx0_s[32 * g + j], Wf[(32 * g + j) * Dd + d], s);
        red[g][d] = s;
    }
    __syncthreads();
    if (t < 128) fixedc_s[t] = red[0][t] + red[1][t] + red[2][t] + red[3][t];
    __syncthreads();

    // ---------------- decode loop: 4 barriers/step ----------------
    unsigned long long vis0 = 0, vis1 = 0, vis2 = 0, vis3 = 0;
    int sel_prev = 0;

    for (int step = 0; step < Nn; ++step) {
        // A') per-wave q: quad-split dot + 2 shuffles + readlane -> SGPRs
        const float* ctxp = (step == 0) ? ctx0_s : (emb_s + sel_prev * Dd);
        float s = 0.f;
        {
            const float4* c4 = (const float4*)(ctxp + 32 * kk);
#pragma unroll
            for (int i4 = 0; i4 < 8; ++i4) {
                const int idx = (i4 + 2 * kk) & 7;           // rotation avoids 4-way bank clash
                float4 c = c4[idx];
                s = fmaf(c.x, ws_r[4 * i4 + 0], s);
                s = fmaf(c.y, ws_r[4 * i4 + 1], s);
                s = fmaf(c.z, ws_r[4 * i4 + 2], s);
                s = fmaf(c.w, ws_r[4 * i4 + 3], s);
            }
        }
        s += __shfl_xor(s, 1);
        s += __shfl_xor(s, 2);                               // quad-sum: all 4 lanes have q_jq
        s = (s + fixedc_s[16 * w + jq]) * QSCALE;            // pre-scale: *1/sqrt(dk)*log2e
        const float q0  = rdlane(s, 0),  q1  = rdlane(s, 4),  q2  = rdlane(s, 8),  q3  = rdlane(s, 12);
        const float q4  = rdlane(s, 16), q5  = rdlane(s, 20), q6  = rdlane(s, 24), q7  = rdlane(s, 28);
        const float q8  = rdlane(s, 32), q9  = rdlane(s, 36), q10 = rdlane(s, 40), q11 = rdlane(s, 44);
        const float q12 = rdlane(s, 48), q13 = rdlane(s, 52), q14 = rdlane(s, 56), q15 = rdlane(s, 60);

#define DOT16(G) (fmaf((G)[0].x,q0, fmaf((G)[0].y,q1, fmaf((G)[0].z,q2, fmaf((G)[0].w,q3, \
                  fmaf((G)[1].x,q4, fmaf((G)[1].y,q5, fmaf((G)[1].z,q6, fmaf((G)[1].w,q7, \
                  fmaf((G)[2].x,q8, fmaf((G)[2].y,q9, fmaf((G)[2].z,q10,fmaf((G)[2].w,q11,\
                  fmaf((G)[3].x,q12,fmaf((G)[3].y,q13,fmaf((G)[3].z,q14,(G)[3].w*q15))))))))))))))))

        // C+D) compat (regs) -> masked exp2 -> store p, wave-sum for norm
        float x0 = DOT16(gk0), x1 = DOT16(gk1), x2 = DOT16(gk2), x3 = DOT16(gk3);
        x0 = ((vis0 >> lane) & 1ull) ? -1e30f : x0;
        x1 = ((vis1 >> lane) & 1ull) ? -1e30f : x1;
        x2 = ((vis2 >> lane) & 1ull) ? -1e30f : x2;
        x3 = (lane < 8 && !((vis3 >> lane) & 1ull)) ? x3 : -1e30f;
        float p0 = exp2f(x0), p1 = exp2f(x1), p2 = exp2f(x2), p3 = exp2f(x3);
        {
            float* prow = &sm2[w][0];
            prow[lane      ] = p0;
            prow[lane +  64] = p1;
            prow[lane + 128] = p2;
            prow[lane + 192] = p3;   // lanes>=8 write 0 into slack (read as zero later)
        }
        float ps = (p0 + p1) + (p2 + p3);
#pragma unroll
        for (int off = 1; off < 64; off <<= 1) ps += __shfl_xor(ps, off);
        if (lane == 0) sums[w] = 1.0f / ps;
        __syncthreads();                                     // B4: sm2, sums ready

        // E) glimpse partials over n-slice [52g, 52g+52)
        {
            const int hd = d >> 4;
            const float* a = &sm2[hd][52 * g];
            float s2 = 0.f;
#pragma unroll
            for (int k4 = 0; k4 < 13; ++k4) {
                float4 av = ((const float4*)a)[k4];
                s2 = fmaf(av.x, gv_r[4 * k4 + 0], s2);
                s2 = fmaf(av.y, gv_r[4 * k4 + 1], s2);
                s2 = fmaf(av.z, gv_r[4 * k4 + 2], s2);
                s2 = fmaf(av.w, gv_r[4 * k4 + 3], s2);
            }
            red[g][d] = s2;
        }
        __syncthreads();                                     // B5: partials ready
        if (t < 128)
            glim_s[t] = (red[0][t] + red[1][t] + red[2][t] + red[3][t]) * sums[t >> 4];
        __syncthreads();                                     // B6: glimpse ready

        // G) logits: t<400, n=t>>1, half j=t&1 -> dot64 + pair shuffle + tanh
        if (t < 400) {
            const int n = t >> 1, jh = t & 1;
            const float4* gl = ((const float4*)glim_s) + 16 * jh;
            float sl = 0.f;
#pragma unroll
            for (int i = 0; i < 16; ++i) sl += dot4(lk_r[i], gl[i]);
            sl += __shfl_xor(sl, 1);
            if (jh == 0) {
                const float xx = sl * inv_sqrt_d;
                const float u  = exp2f(xx * (2.0f * LOG2E));  // e^{2x}
                const float th = 1.0f - 2.0f / (u + 1.0f);    // tanh(x)
                const int w2 = n >> 6, bit = n & 63;
                const unsigned long long mw = (w2 == 0) ? vis0 : (w2 == 1) ? vis1
                                            : (w2 == 2) ? vis2 : vis3;
                logits_s[n] = ((mw >> bit) & 1ull) ? NEG_INF : TANH_CLIP * th;
            }
        }
        __syncthreads();                                     // B7: logits ready

        // H) redundant per-wave argmax (ballot) + lse (fixed max=10, ILP with max chain)
        float v0 = logits_s[lane], v1 = logits_s[lane + 64], v2 = logits_s[lane + 128];
        float v3 = (lane < 8) ? logits_s[lane + 192] : -INFINITY;
        float mx = fmaxf(fmaxf(v0, v1), fmaxf(v2, v3));
        float e0 = exp2f((v0 - 10.f) * LOG2E) + exp2f((v1 - 10.f) * LOG2E)
                 + exp2f((v2 - 10.f) * LOG2E)
                 + ((lane < 8) ? exp2f((v3 - 10.f) * LOG2E) : 0.f);
#pragma unroll
        for (int off = 1; off < 64; off <<= 1) {
            mx = fmaxf(mx, __shfl_xor(mx, off));
            e0 += __shfl_xor(e0, off);
        }
        const unsigned long long b0 = __ballot(v0 == mx);
        const unsigned long long b1 = __ballot(v1 == mx);
        const unsigned long long b2 = __ballot(v2 == mx);
        const unsigned long long b3 = __ballot(v3 == mx);
        const int sel = b0 ? __builtin_ctzll(b0)
                      : b1 ? 64  + __builtin_ctzll(b1)
                      : b2 ? 128 + __builtin_ctzll(b2)
                      :      192 + __builtin_ctzll(b3);
        const float lse = log2f(e0) * LN2 + 10.f;

        // outputs + state (no barrier: next write to any read buffer is >=3 barriers away)
        if (t < 200) out_logp[((size_t)b * Nn + step) * Nn + t] = logits_s[t] - lse;
        if (t == 0)  out_pi[(size_t)b * Nn + step] = (float)sel;
        const unsigned long long sbit = 1ull << (sel & 63);
        const int sw = sel >> 6;
        vis0 |= (sw == 0) ? sbit : 0ull;
        vis1 |= (sw == 1) ? sbit : 0ull;
        vis2 |= (sw == 2) ? sbit : 0ull;
        vis3 |= (sw == 3) ? sbit : 0ull;
        sel_prev = sel;
    }
#undef DOT16
}

// ----------------------------------------------------------------------------
extern "C" void kernel_launch(void* const* d_in, const int* in_sizes, int n_in,
                              void* d_out, int out_size, void* d_ws, size_t ws_size,
                              hipStream_t stream) {
    (void)in_sizes; (void)n_in; (void)out_size; (void)ws_size;
    const float* emb = (const float*)d_in[0];   // [B,N,D]
    const float* Wn  = (const float*)d_in[1];   // [D,3D]
    const float* Wf  = (const float*)d_in[2];   // [D,D]
    const float* Wsp = (const float*)d_in[3];   // [D,D]

    const size_t BND = (size_t)Bsz * Nn * Dd;
    float* gk = (float*)d_ws;
    float* gv = gk + BND;
    float* lk = gv + BND;

    float* out_logp = (float*)d_out;                       // [B,T,N]
    float* out_pi   = out_logp + (size_t)Bsz * Nn * Nn;    // [B,T] as float

    proj_kernel<<<(Bsz * Nn) / 64, 384, 0, stream>>>(emb, Wn, gk, gv, lk);
    decode_kernel<<<Bsz, 512, 0, stream>>>(emb, Wf, Wsp, gk, gv, lk,
                                           out_logp, out_pi);
}

// Round 5
// 1153.918 us; speedup vs baseline: 4.4844x; 1.5653x over previous
//
#include <hip/hip_runtime.h>
#include <math.h>

// GlimpseDecoder: B=512, N=T=200, D=128, H=8, dk=16
// R5 = R4 with proj staging bug fixed (wn_s needs 8 staging iterations).
// decode: 2 barriers/step; qall[n]=emb[n]@W_step precomputed per block;
// wave-private compat+softmax+glimpse; tiled proj.

#define Bsz 512
#define Nn  200
#define Dd  128
#define TANH_CLIP 10.0f
#define NEG_INF  -1e9f
#define LOG2E 1.4426950408889634f
#define LN2   0.6931471805599453f

__device__ __forceinline__ float dot4(float4 a, float4 b) {
    return a.x*b.x + a.y*b.y + a.z*b.z + a.w*b.w;
}
__device__ __forceinline__ float rdlane(float v, int l) {
    union { float f; int i; } u; u.f = v;
    u.i = __builtin_amdgcn_readlane(u.i, l);
    return u.f;
}

// ---------------- Kernel A: tiled proj = emb @ W_node -> gk, gv, lk ----------
// grid = 1600 rowtiles x 3 colgroups; block 256 thr; tile 64 rows x 128 cols.
__global__ __launch_bounds__(256, 3) void proj_kernel(
    const float* __restrict__ emb, const float* __restrict__ Wn,
    float* __restrict__ gk, float* __restrict__ gv, float* __restrict__ lk)
{
    const int bid = blockIdx.x;
    const int cg  = bid % 3;                 // col group: 0->gk,1->gv,2->lk
    const int rowBase = (bid / 3) * 64;
    const int t  = threadIdx.x;
    const int c4 = t & 31;                   // cols 4*c4 .. +3
    const int r8 = t >> 5;                   // rows 8*r8 .. +7

    __shared__ __align__(16) float wn_s[64][128];   // 32 KB  (k-half x col)
    __shared__ __align__(16) float e_s[64][68];     // 17 KB  (row x k-half, pad)

    float acc[8][4];
#pragma unroll
    for (int j = 0; j < 8; ++j)
#pragma unroll
        for (int m = 0; m < 4; ++m) acc[j][m] = 0.f;

    for (int kh = 0; kh < 2; ++kh) {
        // stage Wn half: 64 rows x 128 cols = 2048 f4 -> 8 iters of 256 thr
#pragma unroll
        for (int i = 0; i < 8; ++i) {
            const int idx = t + 256 * i;            // f4 index
            const int kr = idx >> 5, cc = (idx & 31) * 4;
            *(float4*)&wn_s[kr][cc] =
                *(const float4*)&Wn[(size_t)(kh * 64 + kr) * 384 + 128 * cg + cc];
        }
        // stage emb half: 64 rows x 64 k = 1024 f4 -> 4 iters
#pragma unroll
        for (int i = 0; i < 4; ++i) {
            const int idx = t + 256 * i;
            const int rr = idx >> 4, kk4 = (idx & 15) * 4;
            *(float4*)&e_s[rr][kk4] =
                *(const float4*)&emb[(size_t)(rowBase + rr) * Dd + kh * 64 + kk4];
        }
        __syncthreads();

#pragma unroll
        for (int k4 = 0; k4 < 16; ++k4) {
            float4 er[8];
#pragma unroll
            for (int j = 0; j < 8; ++j)
                er[j] = *(const float4*)&e_s[8 * r8 + j][4 * k4];
#pragma unroll
            for (int m = 0; m < 4; ++m) {
                const float4 wv = *(const float4*)&wn_s[4 * k4 + m][4 * c4];
#pragma unroll
                for (int j = 0; j < 8; ++j) {
                    const float ev = (m == 0) ? er[j].x : (m == 1) ? er[j].y
                                   : (m == 2) ? er[j].z : er[j].w;
                    acc[j][0] = fmaf(ev, wv.x, acc[j][0]);
                    acc[j][1] = fmaf(ev, wv.y, acc[j][1]);
                    acc[j][2] = fmaf(ev, wv.z, acc[j][2]);
                    acc[j][3] = fmaf(ev, wv.w, acc[j][3]);
                }
            }
        }
        __syncthreads();
    }

    float* out = (cg == 0) ? gk : (cg == 1) ? gv : lk;
#pragma unroll
    for (int j = 0; j < 8; ++j) {
        float4 v; v.x = acc[j][0]; v.y = acc[j][1]; v.z = acc[j][2]; v.w = acc[j][3];
        *(float4*)&out[(size_t)(rowBase + 8 * r8 + j) * Dd + 4 * c4] = v;
    }
}

// ---------------- Kernel B: greedy decode, 2 barriers/step --------------------
__global__ __launch_bounds__(512, 1) void decode_kernel(
    const float* __restrict__ emb,
    const float* __restrict__ Wf,   // W_fixed [D][D]
    const float* __restrict__ Wsp,  // W_step  [D][D]
    const float* __restrict__ gk, const float* __restrict__ gv,
    const float* __restrict__ lk,
    float* __restrict__ out_logp,   // [B][T][N]
    float* __restrict__ out_pi)     // [B][T] (as float)
{
    const int b    = blockIdx.x;
    const int t    = threadIdx.x;
    const int lane = t & 63;
    const int w    = t >> 6;      // wave id == head
    const int g    = t >> 7;      // 0..3 group (prologue)
    const int d    = t & 127;     // 0..127 col (prologue)
    const int jq   = lane >> 2;   // 0..15 col-within-head
    const int cq   = lane & 3;    // 0..3 quad slot (glimpse n-slice)

    __shared__ __align__(16) float qall_s[201 * Dd];   // 100.5 KB: emb staging -> qall*QSCALE
    __shared__ __align__(16) float wchunk_s[16][Dd];   // 8 KB  (W_step k-chunk)
    __shared__ __align__(16) float sm2[8][256];        // 8 KB  wave-private attn p
    __shared__ __align__(16) float red[4][Dd];         // 2 KB
    __shared__ __align__(16) float ctx0_s[Dd];
    __shared__ __align__(16) float fixedc_s[Dd];       // prescaled by QSCALE
    __shared__ __align__(16) float glim_s[Dd];
    __shared__ __align__(16) float logits_s[Nn];

    const float inv_sqrt_d = 0.08838834764831845f;     // 1/sqrt(128)
    const float QSCALE = 0.25f * LOG2E;                // 1/sqrt(dk) * log2(e)

    const float* embB = emb + (size_t)b * Nn * Dd;
    const float* gkB  = gk  + (size_t)b * Nn * Dd;
    const float* gvB  = gv  + (size_t)b * Nn * Dd;
    const float* lkB  = lk  + (size_t)b * Nn * Dd;

    // ================= prologue =================
    {   // emb -> qall_s rows 0..199
        const float4* e4  = (const float4*)embB;
        float4*       es4 = (float4*)qall_s;
#pragma unroll
        for (int it = 0; it < 12; ++it) es4[t + 512 * it] = e4[t + 512 * it];
        if (t < 256) es4[t + 6144] = e4[t + 6144];
    }
    __syncthreads();

    // ctx0 = mean over 200 rows (thread (g,d): rows 50g..50g+49)
    {
        float s = 0.f;
#pragma unroll
        for (int k = 0; k < 50; ++k) s += qall_s[(50 * g + k) * Dd + d];
        red[g][d] = s;
    }
    __syncthreads();
    if (t < 128) ctx0_s[t] = (red[0][t] + red[1][t] + red[2][t] + red[3][t]) * (1.0f / 200.0f);
    __syncthreads();

    // fixedc = ctx0 @ W_fixed (prescaled), and append ctx0 as row 200
    {
        float s = 0.f;
#pragma unroll
        for (int j = 0; j < 32; ++j)
            s = fmaf(ctx0_s[32 * g + j], Wf[(32 * g + j) * Dd + d], s);
        red[g][d] = s;
    }
    __syncthreads();
    if (t < 128) {
        fixedc_s[t] = (red[0][t] + red[1][t] + red[2][t] + red[3][t]) * QSCALE;
        qall_s[200 * Dd + t] = ctx0_s[t];
    }
    __syncthreads();

    // qall GEMM: rows 52g..52g+51 (clamped <=200), col d; k staged in 8 chunks
    float qr[52];
#pragma unroll
    for (int i = 0; i < 52; ++i) qr[i] = 0.f;

    for (int kc = 0; kc < 8; ++kc) {
        {   // stage W_step rows 16kc..16kc+15, all 128 cols (512 f4, 1/thread)
            const int kr = t >> 5, cc = (t & 31) * 4;
            *(float4*)&wchunk_s[kr][cc] =
                *(const float4*)&Wsp[(size_t)(16 * kc + kr) * Dd + cc];
        }
        __syncthreads();
#pragma unroll
        for (int i = 0; i < 52; ++i) {
            const int r = 52 * g + i;
            if (r < 201) {
#pragma unroll
                for (int j4 = 0; j4 < 4; ++j4) {
                    const float4 ev = *(const float4*)&qall_s[r * Dd + 16 * kc + 4 * j4];
                    qr[i] = fmaf(ev.x, wchunk_s[4 * j4 + 0][d], qr[i]);
                    qr[i] = fmaf(ev.y, wchunk_s[4 * j4 + 1][d], qr[i]);
                    qr[i] = fmaf(ev.z, wchunk_s[4 * j4 + 2][d], qr[i]);
                    qr[i] = fmaf(ev.w, wchunk_s[4 * j4 + 3][d], qr[i]);
                }
            }
        }
        __syncthreads();
    }
    // overwrite qall_s with prescaled q-base
#pragma unroll
    for (int i = 0; i < 52; ++i) {
        const int r = 52 * g + i;
        if (r < 201) qall_s[r * Dd + d] = qr[i] * QSCALE;
    }
    __syncthreads();

    // ---------------- persistent registers ----------------
    float4 gk0[4], gk1[4], gk2[4], gk3[4];  // K frags: head w, n = lane+64k
    float  gv_r[52];                        // V rows 52cq..(+51 clamp), col 16w+jq
    float4 lk_r[16];                        // logit-K: t<400: n=t>>1, half t&1
    {
        const float4* s0 = (const float4*)(gkB + (size_t)(lane      ) * Dd + 16 * w);
        const float4* s1 = (const float4*)(gkB + (size_t)(lane +  64) * Dd + 16 * w);
        const float4* s2 = (const float4*)(gkB + (size_t)(lane + 128) * Dd + 16 * w);
        const int n3 = (lane < 8) ? lane + 192 : 199;
        const float4* s3 = (const float4*)(gkB + (size_t)n3 * Dd + 16 * w);
#pragma unroll
        for (int i = 0; i < 4; ++i) { gk0[i]=s0[i]; gk1[i]=s1[i]; gk2[i]=s2[i]; gk3[i]=s3[i]; }
    }
#pragma unroll
    for (int k = 0; k < 52; ++k) {
        int r = 52 * cq + k; r = r < 200 ? r : 199;
        gv_r[k] = gvB[(size_t)r * Dd + 16 * w + jq];
    }
    if (t < 400) {
        const float4* src = (const float4*)(lkB + (size_t)(t >> 1) * Dd + (t & 1) * 64);
#pragma unroll
        for (int i = 0; i < 16; ++i) lk_r[i] = src[i];
    } else {
#pragma unroll
        for (int i = 0; i < 16; ++i) lk_r[i] = float4{0, 0, 0, 0};
    }
    const float fc_q = fixedc_s[16 * w + jq];   // loop-invariant

    // ================= decode loop: 2 barriers/step =================
    unsigned long long vis0 = 0, vis1 = 0, vis2 = 0, vis3 = 0;
    int sel_prev = 200;                          // row 200 = ctx0 q-base (step 0)

    for (int step = 0; step < Nn; ++step) {
        // q_c (prescaled): 1 LDS read + add; broadcast via readlane
        float s = qall_s[sel_prev * Dd + 16 * w + jq] + fc_q;
        const float q0  = rdlane(s, 0),  q1  = rdlane(s, 4),  q2  = rdlane(s, 8),  q3  = rdlane(s, 12);
        const float q4  = rdlane(s, 16), q5  = rdlane(s, 20), q6  = rdlane(s, 24), q7  = rdlane(s, 28);
        const float q8  = rdlane(s, 32), q9  = rdlane(s, 36), q10 = rdlane(s, 40), q11 = rdlane(s, 44);
        const float q12 = rdlane(s, 48), q13 = rdlane(s, 52), q14 = rdlane(s, 56), q15 = rdlane(s, 60);

#define DOT16(G) (fmaf((G)[0].x,q0, fmaf((G)[0].y,q1, fmaf((G)[0].z,q2, fmaf((G)[0].w,q3, \
                  fmaf((G)[1].x,q4, fmaf((G)[1].y,q5, fmaf((G)[1].z,q6, fmaf((G)[1].w,q7, \
                  fmaf((G)[2].x,q8, fmaf((G)[2].y,q9, fmaf((G)[2].z,q10,fmaf((G)[2].w,q11,\
                  fmaf((G)[3].x,q12,fmaf((G)[3].y,q13,fmaf((G)[3].z,q14,(G)[3].w*q15))))))))))))))))

        // compat (regs, already in log2 domain) -> masked -> p = 2^x
        float x0 = DOT16(gk0), x1 = DOT16(gk1), x2 = DOT16(gk2), x3 = DOT16(gk3);
        x0 = ((vis0 >> lane) & 1ull) ? -1e30f : x0;
        x1 = ((vis1 >> lane) & 1ull) ? -1e30f : x1;
        x2 = ((vis2 >> lane) & 1ull) ? -1e30f : x2;
        x3 = (lane < 8 && !((vis3 >> lane) & 1ull)) ? x3 : -1e30f;
        const float p0 = exp2f(x0), p1 = exp2f(x1), p2 = exp2f(x2), p3 = exp2f(x3);
        {
            float* prow = &sm2[w][0];
            prow[lane      ] = p0;
            prow[lane +  64] = p1;
            prow[lane + 128] = p2;
            prow[lane + 192] = p3;      // n in [200,256): zeros (masked), read as 0
        }
        float ps = (p0 + p1) + (p2 + p3);
#pragma unroll
        for (int off = 1; off < 64; off <<= 1) ps += __shfl_xor(ps, off);
        const float invps = 1.0f / ps;

        // glimpse (wave-private): col 16w+jq, n-slice [52cq, 52cq+52)
        {
            const float* a = &sm2[w][52 * cq];
            float s0 = 0.f, s1 = 0.f, s2 = 0.f, s3 = 0.f;
#pragma unroll
            for (int k4 = 0; k4 < 13; ++k4) {
                const float4 av = ((const float4*)a)[k4];
                s0 = fmaf(av.x, gv_r[4 * k4 + 0], s0);
                s1 = fmaf(av.y, gv_r[4 * k4 + 1], s1);
                s2 = fmaf(av.z, gv_r[4 * k4 + 2], s2);
                s3 = fmaf(av.w, gv_r[4 * k4 + 3], s3);
            }
            float gsum = (s0 + s1) + (s2 + s3);
            gsum += __shfl_xor(gsum, 1);
            gsum += __shfl_xor(gsum, 2);
            if (cq == 0) glim_s[16 * w + jq] = gsum * invps;
        }
        __syncthreads();                                   // B1: glim ready

        // logits: t<400, n=t>>1, half jh=t&1 -> dot64 (4 accs) + pair shuffle
        if (t < 400) {
            const int n = t >> 1, jh = t & 1;
            const float4* gl = ((const float4*)glim_s) + 16 * jh;
            float a0 = 0.f, a1 = 0.f, a2 = 0.f, a3 = 0.f;
#pragma unroll
            for (int i = 0; i < 4; ++i) {
                const float4 l0 = lk_r[4*i+0], l1 = lk_r[4*i+1], l2 = lk_r[4*i+2], l3 = lk_r[4*i+3];
                const float4 g0 = gl[4*i+0],  g1 = gl[4*i+1],  g2 = gl[4*i+2],  g3 = gl[4*i+3];
                a0 = fmaf(l0.x,g0.x, fmaf(l0.y,g0.y, fmaf(l0.z,g0.z, fmaf(l0.w,g0.w, a0))));
                a1 = fmaf(l1.x,g1.x, fmaf(l1.y,g1.y, fmaf(l1.z,g1.z, fmaf(l1.w,g1.w, a1))));
                a2 = fmaf(l2.x,g2.x, fmaf(l2.y,g2.y, fmaf(l2.z,g2.z, fmaf(l2.w,g2.w, a2))));
                a3 = fmaf(l3.x,g3.x, fmaf(l3.y,g3.y, fmaf(l3.z,g3.z, fmaf(l3.w,g3.w, a3))));
            }
            float sl = (a0 + a1) + (a2 + a3);
            sl += __shfl_xor(sl, 1);
            if (jh == 0) {
                const float xx = sl * inv_sqrt_d;
                const float u  = exp2f(xx * (2.0f * LOG2E));  // e^{2x}
                const float th = 1.0f - 2.0f / (u + 1.0f);    // tanh
                const int w2 = n >> 6, bit = n & 63;
                const unsigned long long mw = (w2 == 0) ? vis0 : (w2 == 1) ? vis1
                                            : (w2 == 2) ? vis2 : vis3;
                logits_s[n] = ((mw >> bit) & 1ull) ? NEG_INF : TANH_CLIP * th;
            }
        }
        __syncthreads();                                   // B2: logits ready

        // argmax + lse, redundant per wave (ballot; fixed max = 10)
        const float v0 = logits_s[lane], v1 = logits_s[lane + 64], v2 = logits_s[lane + 128];
        const float v3 = (lane < 8) ? logits_s[lane + 192] : -INFINITY;
        float mx = fmaxf(fmaxf(v0, v1), fmaxf(v2, v3));
        float e0 = exp2f((v0 - 10.f) * LOG2E) + exp2f((v1 - 10.f) * LOG2E)
                 + exp2f((v2 - 10.f) * LOG2E)
                 + ((lane < 8) ? exp2f((v3 - 10.f) * LOG2E) : 0.f);
#pragma unroll
        for (int off = 1; off < 64; off <<= 1) {
            mx = fmaxf(mx, __shfl_xor(mx, off));
            e0 += __shfl_xor(e0, off);
        }
        const unsigned long long b0 = __ballot(v0 == mx);
        const unsigned long long b1 = __ballot(v1 == mx);
        const unsigned long long b2 = __ballot(v2 == mx);
        const unsigned long long b3 = __ballot(v3 == mx);
        const int sel = b0 ? __builtin_ctzll(b0)
                      : b1 ? 64  + __builtin_ctzll(b1)
                      : b2 ? 128 + __builtin_ctzll(b2)
                      :      192 + __builtin_ctzll(b3);
        const float lse = log2f(e0) * LN2 + 10.f;

        // outputs + state (vectorized row write)
        if (t < 50) {
            float4 lv = *(const float4*)&logits_s[4 * t];
            lv.x -= lse; lv.y -= lse; lv.z -= lse; lv.w -= lse;
            *(float4*)&out_logp[((size_t)b * Nn + step) * Nn + 4 * t] = lv;
        }
        if (t == 0) out_pi[(size_t)b * Nn + step] = (float)sel;
        const unsigned long long sbit = 1ull << (sel & 63);
        const int sw = sel >> 6;
        vis0 |= (sw == 0) ? sbit : 0ull;
        vis1 |= (sw == 1) ? sbit : 0ull;
        vis2 |= (sw == 2) ? sbit : 0ull;
        vis3 |= (sw == 3) ? sbit : 0ull;
        sel_prev = sel;
    }
#undef DOT16
}

// ----------------------------------------------------------------------------
extern "C" void kernel_launch(void* const* d_in, const int* in_sizes, int n_in,
                              void* d_out, int out_size, void* d_ws, size_t ws_size,
                              hipStream_t stream) {
    (void)in_sizes; (void)n_in; (void)out_size; (void)ws_size;
    const float* emb = (const float*)d_in[0];   // [B,N,D]
    const float* Wn  = (const float*)d_in[1];   // [D,3D]
    const float* Wf  = (const float*)d_in[2];   // [D,D]
    const float* Wsp = (const float*)d_in[3];   // [D,D]

    const size_t BND = (size_t)Bsz * Nn * Dd;
    float* gk = (float*)d_ws;
    float* gv = gk + BND;
    float* lk = gv + BND;

    float* out_logp = (float*)d_out;                       // [B,T,N]
    float* out_pi   = out_logp + (size_t)Bsz * Nn * Nn;    // [B,T] as float

    proj_kernel<<<(Bsz * Nn / 64) * 3, 256, 0, stream>>>(emb, Wn, gk, gv, lk);
    decode_kernel<<<Bsz, 512, 0, stream>>>(emb, Wf, Wsp, gk, gv, lk,
                                           out_logp, out_pi);
}